// Round 9
// baseline (216.606 us; speedup 1.0000x reference)
//
#include <hip/hip_runtime.h>

#define SS 4096
#define DD 1024
#define LL 16

typedef __attribute__((ext_vector_type(8))) short short8;
typedef __attribute__((ext_vector_type(4))) float fl4;
typedef __attribute__((ext_vector_type(2))) float fl2;

static __device__ __forceinline__ short f2bf(float f) {
    // round-to-nearest-even fp32 -> bf16 (inputs finite)
    unsigned u = __float_as_uint(f);
    u += 0x7FFFu + ((u >> 16) & 1u);
    return (short)(u >> 16);
}

static __device__ __forceinline__ short8 pack8(fl4 a, fl4 b) {
    short8 r;
    r[0] = f2bf(a[0]); r[1] = f2bf(a[1]); r[2] = f2bf(a[2]); r[3] = f2bf(a[3]);
    r[4] = f2bf(b[0]); r[5] = f2bf(b[1]); r[6] = f2bf(b[2]); r[7] = f2bf(b[3]);
    return r;
}

// 512 blocks x 512 thr (8 waves). NO mem-LDS staging, NO vmcnt asm, NO
// DMA lockstep. Cost-model (R4/R6 solved): fixed harness ~128us + k_out;
// k_main was ~70us at 1.9 TB/s, 80% idle (R3 PMC: VALU 12%, occ 22%) --
// stall-bound on 8-wave vmcnt/barrier lockstep. Here every wave streams
// independently: wave wv reads its score K-slice [wv*128,+128) straight
// from global (cold, HBM), and its PV d-slice is THE SAME BYTES re-read
// ~1us later (L2/L3-hot). Compiler-managed waits; waves only meet at two
// cheap per-chunk barriers (scr ready, e ready). LDS = 18 KB -> 2 blocks/CU,
// 16 waves/CU of TLP fill the remaining stalls.
// Per chunk c (16 s): scores 4x mfma_16x16x32_bf16 -> scr[c&1] -> lgkm+bar
// -> wave0: sum 8 partials, exp -> e_lds[c&1], zacc -> lgkm+bar -> PV:
// lane owns d-pair wv*128+lane*2, 16 x fl2 global loads (hot) x 16 l FMA.
// MFMA D layout: col(s)=lane&15, row(l)=(lane>>4)*4+reg  [m89-verified]
__global__ __launch_bounds__(512) void k_main(const float* __restrict__ mem,
                                              const float* __restrict__ summ,
                                              float* __restrict__ part,
                                              float* __restrict__ Zpart) {
    __shared__ float scr[2][8][256];     // 16 KB, parity double-buffered
    __shared__ float e_lds[2][16][LL];   // 2 KB

    int blk = blockIdx.x;                // 512 = 8 b x 64 segments
    int b   = blk >> 6;
    int s0  = (blk & 63) << 6;           // 64 s per block
    int t    = threadIdx.x;
    int wv   = t >> 6;                   // 0..7
    int lane = t & 63;
    int o  = lane & 15;
    int qd = lane >> 4;

    // A-frags once per kernel: summ rows o, K-slice [wv*128,+128)
    short8 afr[4];
    {
        const float* arow = summ + o * DD + wv * 128 + qd * 8;
        #pragma unroll
        for (int j = 0; j < 4; ++j) {
            fl4 a0 = *(const fl4*)(arow + j * 32);
            fl4 a1 = *(const fl4*)(arow + j * 32 + 4);
            afr[j] = pack8(a0, a1);
        }
    }

    fl2 ctx[LL];
    #pragma unroll
    for (int l = 0; l < LL; ++l) ctx[l] = (fl2){0.f, 0.f};
    fl4 zacc = {0.f, 0.f, 0.f, 0.f};
    const float scale = 0.03125f;        // 1/sqrt(1024)

    const float* gb = mem + ((size_t)b * SS + s0) * DD;

    #pragma unroll 2
    for (int c = 0; c < 4; ++c) {
        // ---- scores(c): rows s0+c*16+o, cols [wv*128,+128), cold global ----
        const float* brow = gb + (size_t)(c * 16 + o) * DD + wv * 128 + qd * 8;
        fl4 acc = {0.f, 0.f, 0.f, 0.f};
        #pragma unroll
        for (int j = 0; j < 4; ++j) {
            fl4 f0 = *(const fl4*)(brow + j * 32);
            fl4 f1 = *(const fl4*)(brow + j * 32 + 4);
            acc = __builtin_amdgcn_mfma_f32_16x16x32_bf16(afr[j], pack8(f0, f1),
                                                          acc, 0, 0, 0);
        }
        *(fl4*)&scr[c & 1][wv][lane * 4] = acc;
        asm volatile("s_waitcnt lgkmcnt(0)" ::: "memory");
        __builtin_amdgcn_s_barrier();     // scr[c&1] visible
        __builtin_amdgcn_sched_barrier(0);

        // ---- softmax-numerator: wave0 sums 8 K-partials, exp ----
        if (wv == 0) {
            fl4 sum = {0.f, 0.f, 0.f, 0.f};
            #pragma unroll
            for (int w8 = 0; w8 < 8; ++w8)
                sum += *(const fl4*)&scr[c & 1][w8][lane * 4];
            fl4 ev;
            #pragma unroll
            for (int r = 0; r < 4; ++r) ev[r] = __expf(sum[r] * scale);
            *(fl4*)&e_lds[c & 1][o][qd * 4] = ev;   // e[s=o][l=qd*4+r]
            zacc += ev;
        }
        asm volatile("s_waitcnt lgkmcnt(0)" ::: "memory");
        __builtin_amdgcn_s_barrier();     // e_lds[c&1] ready
        __builtin_amdgcn_sched_barrier(0);

        // ---- PV(c): lane owns d-pair wv*128+lane*2 == bytes of its own
        //      score K-slice (just touched -> L2/L3-hot) ----
        const float* mrow = gb + (size_t)(c * 16) * DD + wv * 128 + lane * 2;
        #pragma unroll 4
        for (int s = 0; s < 16; ++s) {
            fl2 m2 = *(const fl2*)(mrow + (size_t)s * DD);
            #pragma unroll
            for (int g4 = 0; g4 < 4; ++g4) {
                fl4 e4 = *(const fl4*)&e_lds[c & 1][s][g4 * 4];  // broadcast
                ctx[g4 * 4 + 0] += e4[0] * m2;
                ctx[g4 * 4 + 1] += e4[1] * m2;
                ctx[g4 * 4 + 2] += e4[2] * m2;
                ctx[g4 * 4 + 3] += e4[3] * m2;
            }
        }
    }

    // Unnormalized ctx partials; layout = [blk][l][d], d = wv*128+lane*2
    float* pp = part + (size_t)blk * LL * DD + wv * 128 + lane * 2;
    #pragma unroll
    for (int l = 0; l < LL; ++l) *(fl2*)(pp + (size_t)l * DD) = ctx[l];

    // Z: wave0 holds zacc for (s=o, l=qd*4+r); reduce over the 16 s lanes
    if (wv == 0) {
        #pragma unroll
        for (int r = 0; r < 4; ++r) {
            float v = zacc[r];
            v += __shfl_xor(v, 1, 64);
            v += __shfl_xor(v, 2, 64);
            v += __shfl_xor(v, 4, 64);
            v += __shfl_xor(v, 8, 64);
            zacc[r] = v;
        }
        if (o == 0) *(fl4*)&Zpart[blk * LL + qd * 4] = zacc;  // lanes 0,16,32,48
    }
}

// out[b][d] = sum_l (w[l] / sum_seg Zpart) * sum_seg part[b*64+seg][l][d]
// 256 blocks x 256 thr; fl4 loads (16B/lane); 64 segs, 2 per thread
__global__ __launch_bounds__(256) void k_out(const float* __restrict__ part,
                                             const float* __restrict__ Zpart,
                                             const float* __restrict__ w,
                                             float* __restrict__ out) {
    int blkid = blockIdx.x;          // 256 = 8 b x 32 d-chunks of 32
    int b  = blkid >> 5;
    int d0 = (blkid & 31) << 5;
    int t = threadIdx.x;
    __shared__ float coef[LL];
    __shared__ fl4 red[32][8];       // [thread-group][d-quad]

    if (t < LL) {
        float Z = 0.f;
        #pragma unroll
        for (int s = 0; s < 64; ++s) Z += Zpart[(b * 64 + s) * LL + t];
        coef[t] = w[t] / Z;
    }
    __syncthreads();

    int dq = t & 7;                  // d-quad within 32-d chunk
    int sg = t >> 3;                 // 0..31; handles segs sg and sg+32
    fl4 acc = {0.f, 0.f, 0.f, 0.f};
    #pragma unroll
    for (int h = 0; h < 2; ++h) {
        const float* pb = part + (size_t)(b * 64 + sg + h * 32) * LL * DD + d0 + dq * 4;
        #pragma unroll
        for (int l = 0; l < LL; ++l) {
            fl4 v = *(const fl4*)(pb + (size_t)l * DD);
            acc += coef[l] * v;
        }
    }
    red[sg][dq] = acc;
    __syncthreads();

    if (t < 8) {
        fl4 s = {0.f, 0.f, 0.f, 0.f};
        #pragma unroll
        for (int g = 0; g < 32; ++g) s += red[g][t];
        *(fl4*)&out[b * DD + d0 + t * 4] = s;
    }
}

extern "C" void kernel_launch(void* const* d_in, const int* in_sizes, int n_in,
                              void* d_out, int out_size, void* d_ws, size_t ws_size,
                              hipStream_t stream) {
    const float* mem  = (const float*)d_in[0];  // [8,4096,1024] fp32
    const float* summ = (const float*)d_in[1];  // [16,1024] fp32
    const float* w    = (const float*)d_in[2];  // [1,16] fp32
    float* out = (float*)d_out;                 // [8,1024] fp32

    char* ws = (char*)d_ws;
    float* Zpart = (float*)ws;                  // 512*16 fl = 32 KB (pad to 64K)
    float* part  = (float*)(ws + 64 * 1024);    // 512*16*1024 fl = 32 MB

    k_main<<<512, 512, 0, stream>>>(mem, summ, part, Zpart);
    k_out<<<256, 256, 0, stream>>>(part, Zpart, w, out);
}